// Round 3
// baseline (313.809 us; speedup 1.0000x reference)
//
#include <hip/hip_runtime.h>
#include <hip/hip_bf16.h>
#include <stdint.h>

typedef unsigned short u16;

#define NINF (-__builtin_huge_valf())

__device__ __forceinline__ float bf2f(u16 h) {
    return __uint_as_float(((unsigned int)h) << 16);
}
__device__ __forceinline__ u16 f2bf(float f) {
    unsigned int u = __float_as_uint(f);
    u += 0x7FFFu + ((u >> 16) & 1u);   // round-to-nearest-even
    return (u16)(u >> 16);
}
__device__ __forceinline__ void unpack8(uint4 u, float* f) {
    f[0] = __uint_as_float(u.x << 16);
    f[1] = __uint_as_float(u.x & 0xFFFF0000u);
    f[2] = __uint_as_float(u.y << 16);
    f[3] = __uint_as_float(u.y & 0xFFFF0000u);
    f[4] = __uint_as_float(u.z << 16);
    f[5] = __uint_as_float(u.z & 0xFFFF0000u);
    f[6] = __uint_as_float(u.w << 16);
    f[7] = __uint_as_float(u.w & 0xFFFF0000u);
}
__device__ __forceinline__ void unpack4(uint2 u, float* f) {
    f[0] = __uint_as_float(u.x << 16);
    f[1] = __uint_as_float(u.x & 0xFFFF0000u);
    f[2] = __uint_as_float(u.y << 16);
    f[3] = __uint_as_float(u.y & 0xFFFF0000u);
}

// ---------------------------------------------------------------------------
// Kernel 1a: proj_equi[b,k,d,o] = sum_c v_equi[b,k,d,c] * W_coord[o,c]
// grid = B*N blocks, 192 threads (d,o). fp32 in -> bf16 out (ws)
// ---------------------------------------------------------------------------
__global__ __launch_bounds__(192) void k_proj_equi(
    const float* __restrict__ v_equi,   // [B*N, 3, 64] fp32
    const float* __restrict__ W_coord,  // [64, 64] (o,c) fp32
    u16* __restrict__ proj)             // [B*N, 3, 64] (d,o) bf16
{
    int bk = blockIdx.x;
    int t = threadIdx.x;
    __shared__ float vs[192];
    vs[t] = v_equi[(size_t)bk * 192 + t];
    __syncthreads();
    int d = t >> 6, o = t & 63;
    float acc = 0.f;
    const float* wrow = W_coord + o * 64;
#pragma unroll
    for (int c = 0; c < 64; c += 4) {
        float4 w = *(const float4*)(wrow + c);
        acc += vs[d * 64 + c + 0] * w.x;
        acc += vs[d * 64 + c + 1] * w.y;
        acc += vs[d * 64 + c + 2] * w.z;
        acc += vs[d * 64 + c + 3] * w.w;
    }
    proj[(size_t)bk * 192 + t] = f2bf(acc);
}

// ---------------------------------------------------------------------------
// Kernel 1b: Y[r,o] = sum_i X[r,i]*W[o,i] + bias[o], fp32 in -> bf16 out (ws)
// block = 8 rows, 256 threads (one per o)
// ---------------------------------------------------------------------------
__global__ __launch_bounds__(256) void k_rowgemm_tobf16(
    const float* __restrict__ X,     // [2048, 256] fp32
    const float* __restrict__ W,     // [256, 256] (o,i) fp32
    const float* __restrict__ bias,  // [256] fp32
    u16* __restrict__ Y)             // [2048, 256] bf16
{
    int r0 = blockIdx.x * 8;
    int t = threadIdx.x;
    __shared__ float Xs[8][256];
#pragma unroll
    for (int i = 0; i < 8; ++i)
        Xs[i][t] = X[(size_t)(r0 + i) * 256 + t];
    __syncthreads();
    float acc[8];
    float bv = bias[t];
#pragma unroll
    for (int r = 0; r < 8; ++r) acc[r] = bv;
    const float* wrow = W + t * 256;
    for (int i = 0; i < 256; i += 4) {
        float4 w = *(const float4*)(wrow + i);
#pragma unroll
        for (int r = 0; r < 8; ++r) {
            acc[r] += Xs[r][i + 0] * w.x;
            acc[r] += Xs[r][i + 1] * w.y;
            acc[r] += Xs[r][i + 2] * w.z;
            acc[r] += Xs[r][i + 3] * w.w;
        }
    }
#pragma unroll
    for (int r = 0; r < 8; ++r)
        Y[(size_t)(r0 + r) * 256 + t] = f2bf(acc[r]);
}

// ---------------------------------------------------------------------------
// Kernel 4: same GEMM but fp32 output into d_out (final inv_updates)
// ---------------------------------------------------------------------------
__global__ __launch_bounds__(256) void k_rowgemm_tof32(
    const float* __restrict__ X,     // [2048, 256] fp32 (ws)
    const float* __restrict__ W,     // [256, 256] (o,i) fp32
    const float* __restrict__ bias,  // [256] fp32
    float* __restrict__ Y)           // [2048, 256] fp32
{
    int r0 = blockIdx.x * 8;
    int t = threadIdx.x;
    __shared__ float Xs[8][256];
#pragma unroll
    for (int i = 0; i < 8; ++i)
        Xs[i][t] = X[(size_t)(r0 + i) * 256 + t];
    __syncthreads();
    float acc[8];
    float bv = bias[t];
#pragma unroll
    for (int r = 0; r < 8; ++r) acc[r] = bv;
    const float* wrow = W + t * 256;
    for (int i = 0; i < 256; i += 4) {
        float4 w = *(const float4*)(wrow + i);
#pragma unroll
        for (int r = 0; r < 8; ++r) {
            acc[r] += Xs[r][i + 0] * w.x;
            acc[r] += Xs[r][i + 1] * w.y;
            acc[r] += Xs[r][i + 2] * w.z;
            acc[r] += Xs[r][i + 3] * w.w;
        }
    }
#pragma unroll
    for (int r = 0; r < 8; ++r)
        Y[(size_t)(r0 + r) * 256 + t] = acc[r];
}

// ---------------------------------------------------------------------------
// Kernel 2: equi attention, one block per (b,q).
// thread: kk = t>>3 (k-group 0..31), g = t&7 (channels g*8..g*8+7)
// single pass: e = exp(msg + mask); s, s2, a_d = sum_k e * proj[k,d,c]
// out_e[d,c] = a_d * sqrt(s2) / s^2 ; epilogue x W_equi_out^T + b -> fp32
// ---------------------------------------------------------------------------
__global__ __launch_bounds__(256) void k_equi_attn(
    const float* __restrict__ equi_msg, // [B,256,256,64] fp32
    const int* __restrict__ adj,        // [B,256,256]
    const u16* __restrict__ proj,       // [B,256,3,64] bf16 (ws)
    const float* __restrict__ W_eo,     // [64,64] (o,c) fp32
    const float* __restrict__ b_eo,     // [64] fp32
    float* __restrict__ out)            // [B,256,3,64] fp32
{
    int bq = blockIdx.x;
    int b = bq >> 8;
    int t = threadIdx.x;

    __shared__ float maskv[256];
    __shared__ int anyflag;
    __shared__ float part[32][195];    // [kk][slot*65 + c], reused in 2 phases
    __shared__ float red_s[64], red_s2[64];
    __shared__ float out_s[3][64];

    if (t == 0) anyflag = 0;
    __syncthreads();
    int a = adj[(size_t)bq * 256 + t];
    if (a != 0) anyflag = 1;
    __syncthreads();
    maskv[t] = (a == 0 && anyflag != 0) ? NINF : 0.0f;
    __syncthreads();

    int kk = t >> 3;
    int c0 = (t & 7) * 8;
    float s[8], s2[8], a0[8], a1[8], a2[8];
#pragma unroll
    for (int u = 0; u < 8; ++u) { s[u] = 0.f; s2[u] = 0.f; a0[u] = 0.f; a1[u] = 0.f; a2[u] = 0.f; }

    const float* msg_base = equi_msg + (size_t)bq * 256 * 64;
    const u16* proj_base = proj + (size_t)b * 256 * 192;

#pragma unroll 4
    for (int j = 0; j < 8; ++j) {
        int k = kk + 32 * j;
        float m = maskv[k];
        float4 m0 = *(const float4*)(msg_base + k * 64 + c0);
        float4 m1 = *(const float4*)(msg_base + k * 64 + c0 + 4);
        const u16* pb = proj_base + k * 192 + c0;
        uint4 up0 = *(const uint4*)(pb);
        uint4 up1 = *(const uint4*)(pb + 64);
        uint4 up2 = *(const uint4*)(pb + 128);
        float mv[8], p0[8], p1[8], p2[8];
        mv[0] = m0.x; mv[1] = m0.y; mv[2] = m0.z; mv[3] = m0.w;
        mv[4] = m1.x; mv[5] = m1.y; mv[6] = m1.z; mv[7] = m1.w;
        unpack8(up0, p0); unpack8(up1, p1); unpack8(up2, p2);
#pragma unroll
        for (int u = 0; u < 8; ++u) {
            float e = __expf(mv[u] + m);
            s[u] += e;
            s2[u] += e * e;
            a0[u] += e * p0[u];
            a1[u] += e * p1[u];
            a2[u] += e * p2[u];
        }
    }

    // phase 1 reduce: s, s2 over the 32 k-groups
#pragma unroll
    for (int u = 0; u < 8; ++u) {
        part[kk][c0 + u] = s[u];
        part[kk][65 + c0 + u] = s2[u];
    }
    __syncthreads();
    if (t < 128) {
        int qq = t >> 6, c = t & 63;
        float sum = 0.f;
#pragma unroll
        for (int x = 0; x < 32; ++x) sum += part[x][qq * 65 + c];
        if (qq == 0) red_s[c] = sum; else red_s2[c] = sum;
    }
    __syncthreads();
    // phase 2 reduce: a0,a1,a2
#pragma unroll
    for (int u = 0; u < 8; ++u) {
        part[kk][c0 + u] = a0[u];
        part[kk][65 + c0 + u] = a1[u];
        part[kk][130 + c0 + u] = a2[u];
    }
    __syncthreads();
    if (t < 192) {
        int d = t >> 6, c = t & 63;
        float sum = 0.f;
#pragma unroll
        for (int x = 0; x < 32; ++x) sum += part[x][d * 65 + c];
        float sv = red_s[c];
        float scale = sqrtf(red_s2[c]) / (sv * sv);
        out_s[d][c] = sum * scale;
    }
    __syncthreads();
    // epilogue: [3,64] x W_eo^T + b_eo
    if (t < 192) {
        int d = t >> 6, o = t & 63;
        float acc = b_eo[o];
        const float* wr = W_eo + o * 64;
#pragma unroll
        for (int c4 = 0; c4 < 64; c4 += 4) {
            float4 w = *(const float4*)(wr + c4);
            acc += out_s[d][c4 + 0] * w.x;
            acc += out_s[d][c4 + 1] * w.y;
            acc += out_s[d][c4 + 2] * w.z;
            acc += out_s[d][c4 + 3] * w.w;
        }
        out[(size_t)bq * 192 + t] = acc;
    }
}

// ---------------------------------------------------------------------------
// Kernel 3: inv attention, one block per (b,q).
// pass 1: p[k,h] = exp(msg + mask) into LDS; s,s2 per head
// pass 2: out_i[h,e] = sum_k p[k,h]*proj_inv[b,k,h*16+e]; scale; fp32 -> ws
// ---------------------------------------------------------------------------
__global__ __launch_bounds__(256) void k_inv_attn(
    const float* __restrict__ inv_msg,  // [B,256,256,16] fp32
    const int* __restrict__ adj,        // [B,256,256]
    const u16* __restrict__ proj,       // [B,256,256] bf16 (ws)
    float* __restrict__ out_rows)       // [2048,256] fp32 (ws)
{
    int bq = blockIdx.x;
    int b = bq >> 8;
    int t = threadIdx.x;

    __shared__ float maskv[256];
    __shared__ int anyflag;
    __shared__ float p_s[256][16];
    __shared__ float spart[16][16], s2part[16][16];
    __shared__ float sh_s[16], sh_s2[16];
    __shared__ float red[4][256];

    if (t == 0) anyflag = 0;
    __syncthreads();
    int a = adj[(size_t)bq * 256 + t];
    if (a != 0) anyflag = 1;
    __syncthreads();
    maskv[t] = (a == 0 && anyflag != 0) ? NINF : 0.0f;
    __syncthreads();

    // pass 1
    {
        int h = t & 15, kk = t >> 4;
        float ss = 0.f, ss2 = 0.f;
        const float* mb = inv_msg + (size_t)bq * 256 * 16;
#pragma unroll
        for (int j = 0; j < 16; ++j) {
            int k = kk + 16 * j;
            float e = __expf(mb[k * 16 + h] + maskv[k]);
            p_s[k][h] = e;
            ss += e;
            ss2 += e * e;
        }
        spart[kk][h] = ss;
        s2part[kk][h] = ss2;
    }
    __syncthreads();
    if (t < 32) {
        int h = t & 15;
        float sum = 0.f;
        if (t < 16) {
#pragma unroll
            for (int kk = 0; kk < 16; ++kk) sum += spart[kk][h];
            sh_s[h] = sum;
        } else {
#pragma unroll
            for (int kk = 0; kk < 16; ++kk) sum += s2part[kk][h];
            sh_s2[h] = sum;
        }
    }
    __syncthreads();

    // pass 2
    {
        int kk2 = t >> 6, h = (t >> 2) & 15, eg = t & 3;
        float acc[4] = {0.f, 0.f, 0.f, 0.f};
        const u16* pb = proj + (size_t)b * 256 * 256 + h * 16 + eg * 4;
        for (int j = 0; j < 64; ++j) {
            int k = kk2 + 4 * j;
            float p = p_s[k][h];
            uint2 u = *(const uint2*)(pb + k * 256);
            float w[4]; unpack4(u, w);
            acc[0] += p * w[0];
            acc[1] += p * w[1];
            acc[2] += p * w[2];
            acc[3] += p * w[3];
        }
#pragma unroll
        for (int ii = 0; ii < 4; ++ii) red[kk2][h * 16 + eg * 4 + ii] = acc[ii];
    }
    __syncthreads();
    {
        float sum = red[0][t] + red[1][t] + red[2][t] + red[3][t];
        int h = t >> 4;
        float sv = sh_s[h];
        out_rows[(size_t)bq * 256 + t] = sum * sqrtf(sh_s2[h]) / (sv * sv);
    }
}

// ---------------------------------------------------------------------------
extern "C" void kernel_launch(void* const* d_in, const int* in_sizes, int n_in,
                              void* d_out, int out_size, void* d_ws, size_t ws_size,
                              hipStream_t stream) {
    (void)in_sizes; (void)n_in; (void)out_size; (void)ws_size;

    const float* v_equi   = (const float*)d_in[0];
    const float* v_inv    = (const float*)d_in[1];
    const float* equi_msg = (const float*)d_in[2];
    const float* inv_msg  = (const float*)d_in[3];
    const int*   adj      = (const int*)d_in[4];
    const float* W_coord  = (const float*)d_in[5];
    const float* W_eo     = (const float*)d_in[6];
    const float* b_eo     = (const float*)d_in[7];
    const float* W_in     = (const float*)d_in[8];
    const float* b_in     = (const float*)d_in[9];
    const float* W_out    = (const float*)d_in[10];
    const float* b_out    = (const float*)d_in[11];
    float* out = (float*)d_out;

    char* ws = (char*)d_ws;
    u16*   proj_equi = (u16*)(ws);                        // 786432 B
    u16*   proj_inv  = (u16*)(ws + 786432);               // 1048576 B
    float* out_rows  = (float*)(ws + 786432 + 1048576);   // 2097152 B

    k_proj_equi<<<dim3(2048), dim3(192), 0, stream>>>(v_equi, W_coord, proj_equi);
    k_rowgemm_tobf16<<<dim3(256), dim3(256), 0, stream>>>(v_inv, W_in, b_in, proj_inv);
    k_equi_attn<<<dim3(2048), dim3(256), 0, stream>>>(equi_msg, adj, proj_equi, W_eo, b_eo, out);
    k_inv_attn<<<dim3(2048), dim3(256), 0, stream>>>(inv_msg, adj, proj_inv, out_rows);
    k_rowgemm_tof32<<<dim3(256), dim3(256), 0, stream>>>(out_rows, W_out, b_out, out + 393216);
}

// Round 4
// 291.825 us; speedup vs baseline: 1.0753x; 1.0753x over previous
//
#include <hip/hip_runtime.h>
#include <hip/hip_bf16.h>
#include <stdint.h>

typedef unsigned short u16;

#define NINF (-__builtin_huge_valf())

__device__ __forceinline__ float bf2f(u16 h) {
    return __uint_as_float(((unsigned int)h) << 16);
}
__device__ __forceinline__ u16 f2bf(float f) {
    unsigned int u = __float_as_uint(f);
    u += 0x7FFFu + ((u >> 16) & 1u);   // round-to-nearest-even
    return (u16)(u >> 16);
}
__device__ __forceinline__ void unpack8(uint4 u, float* f) {
    f[0] = __uint_as_float(u.x << 16);
    f[1] = __uint_as_float(u.x & 0xFFFF0000u);
    f[2] = __uint_as_float(u.y << 16);
    f[3] = __uint_as_float(u.y & 0xFFFF0000u);
    f[4] = __uint_as_float(u.z << 16);
    f[5] = __uint_as_float(u.z & 0xFFFF0000u);
    f[6] = __uint_as_float(u.w << 16);
    f[7] = __uint_as_float(u.w & 0xFFFF0000u);
}
__device__ __forceinline__ void unpack4(uint2 u, float* f) {
    f[0] = __uint_as_float(u.x << 16);
    f[1] = __uint_as_float(u.x & 0xFFFF0000u);
    f[2] = __uint_as_float(u.y << 16);
    f[3] = __uint_as_float(u.y & 0xFFFF0000u);
}

// ---------------------------------------------------------------------------
// Prologue (fused): blocks [0,256)   -> proj_inv = v_inv @ W_in^T + b_in (bf16)
//                   blocks [256,640) -> proj_equi = v_equi @ W_coord^T  (bf16)
// ---------------------------------------------------------------------------
__global__ __launch_bounds__(256) void k_prologue(
    const float* __restrict__ v_inv,    // [2048, 256]
    const float* __restrict__ W_in,     // [256, 256] (o,i)
    const float* __restrict__ b_in,     // [256]
    u16* __restrict__ proj_inv,         // [2048, 256] bf16
    const float* __restrict__ v_equi,   // [6144, 64] (rows = b*n*3)
    const float* __restrict__ W_coord,  // [64, 64] (o,c)
    u16* __restrict__ proj_equi)        // [6144, 64] bf16
{
    int t = threadIdx.x;
    __shared__ float Xs[8][256];
    __shared__ float Es[16][64];

    if (blockIdx.x < 256) {
        int r0 = blockIdx.x * 8;
#pragma unroll
        for (int i = 0; i < 8; ++i)
            Xs[i][t] = v_inv[(size_t)(r0 + i) * 256 + t];
        __syncthreads();
        float acc[8];
        float bv = b_in[t];
#pragma unroll
        for (int r = 0; r < 8; ++r) acc[r] = bv;
        const float* wrow = W_in + t * 256;
        for (int i = 0; i < 256; i += 4) {
            float4 w = *(const float4*)(wrow + i);
#pragma unroll
            for (int r = 0; r < 8; ++r) {
                acc[r] += Xs[r][i + 0] * w.x;
                acc[r] += Xs[r][i + 1] * w.y;
                acc[r] += Xs[r][i + 2] * w.z;
                acc[r] += Xs[r][i + 3] * w.w;
            }
        }
#pragma unroll
        for (int r = 0; r < 8; ++r)
            proj_inv[(size_t)(r0 + r) * 256 + t] = f2bf(acc[r]);
    } else {
        int bi = blockIdx.x - 256;            // [0,384), 16 rows each
        const float* src = v_equi + (size_t)bi * 1024;
        ((float4*)Es)[t] = *(const float4*)(src + t * 4);
        __syncthreads();
        int o = t & 63, rr = t >> 6;
        float acc[4] = {0.f, 0.f, 0.f, 0.f};
        const float* wrow = W_coord + o * 64;
#pragma unroll
        for (int c = 0; c < 64; c += 4) {
            float4 w = *(const float4*)(wrow + c);
#pragma unroll
            for (int m = 0; m < 4; ++m) {
                int r = rr + 4 * m;
                acc[m] += Es[r][c + 0] * w.x + Es[r][c + 1] * w.y
                        + Es[r][c + 2] * w.z + Es[r][c + 3] * w.w;
            }
        }
        u16* dst = proj_equi + (size_t)bi * 1024;
#pragma unroll
        for (int m = 0; m < 4; ++m)
            dst[(rr + 4 * m) * 64 + o] = f2bf(acc[m]);
    }
}

// ---------------------------------------------------------------------------
// Final epilogue GEMM: Y[r,o] = sum_i X[r,i]*W[o,i] + bias[o], fp32 -> fp32
// ---------------------------------------------------------------------------
__global__ __launch_bounds__(256) void k_rowgemm_tof32(
    const float* __restrict__ X,     // [2048, 256] fp32 (ws)
    const float* __restrict__ W,     // [256, 256] (o,i)
    const float* __restrict__ bias,  // [256]
    float* __restrict__ Y)           // [2048, 256] fp32
{
    int r0 = blockIdx.x * 8;
    int t = threadIdx.x;
    __shared__ float Xs[8][256];
#pragma unroll
    for (int i = 0; i < 8; ++i)
        Xs[i][t] = X[(size_t)(r0 + i) * 256 + t];
    __syncthreads();
    float acc[8];
    float bv = bias[t];
#pragma unroll
    for (int r = 0; r < 8; ++r) acc[r] = bv;
    const float* wrow = W + t * 256;
    for (int i = 0; i < 256; i += 4) {
        float4 w = *(const float4*)(wrow + i);
#pragma unroll
        for (int r = 0; r < 8; ++r) {
            acc[r] += Xs[r][i + 0] * w.x;
            acc[r] += Xs[r][i + 1] * w.y;
            acc[r] += Xs[r][i + 2] * w.z;
            acc[r] += Xs[r][i + 3] * w.w;
        }
    }
#pragma unroll
    for (int r = 0; r < 8; ++r)
        Y[(size_t)(r0 + r) * 256 + t] = acc[r];
}

// ---------------------------------------------------------------------------
// Equi attention, one block per (b,q). Unchanged from round 3 (near HBM floor).
// ---------------------------------------------------------------------------
__global__ __launch_bounds__(256) void k_equi_attn(
    const float* __restrict__ equi_msg, // [B,256,256,64] fp32
    const int* __restrict__ adj,        // [B,256,256]
    const u16* __restrict__ proj,       // [B,256,3,64] bf16 (ws)
    const float* __restrict__ W_eo,     // [64,64] (o,c)
    const float* __restrict__ b_eo,     // [64]
    float* __restrict__ out)            // [B,256,3,64] fp32
{
    int bq = blockIdx.x;
    int b = bq >> 8;
    int t = threadIdx.x;

    __shared__ float maskv[256];
    __shared__ int anyflag;
    __shared__ float part[32][195];
    __shared__ float red_s[64], red_s2[64];
    __shared__ float out_s[3][64];

    if (t == 0) anyflag = 0;
    __syncthreads();
    int a = adj[(size_t)bq * 256 + t];
    if (a != 0) anyflag = 1;
    __syncthreads();
    maskv[t] = (a == 0 && anyflag != 0) ? NINF : 0.0f;
    __syncthreads();

    int kk = t >> 3;
    int c0 = (t & 7) * 8;
    float s[8], s2[8], a0[8], a1[8], a2[8];
#pragma unroll
    for (int u = 0; u < 8; ++u) { s[u] = 0.f; s2[u] = 0.f; a0[u] = 0.f; a1[u] = 0.f; a2[u] = 0.f; }

    const float* msg_base = equi_msg + (size_t)bq * 256 * 64;
    const u16* proj_base = proj + (size_t)b * 256 * 192;

#pragma unroll 4
    for (int j = 0; j < 8; ++j) {
        int k = kk + 32 * j;
        float m = maskv[k];
        float4 m0 = *(const float4*)(msg_base + k * 64 + c0);
        float4 m1 = *(const float4*)(msg_base + k * 64 + c0 + 4);
        const u16* pb = proj_base + k * 192 + c0;
        uint4 up0 = *(const uint4*)(pb);
        uint4 up1 = *(const uint4*)(pb + 64);
        uint4 up2 = *(const uint4*)(pb + 128);
        float mv[8], p0[8], p1[8], p2[8];
        mv[0] = m0.x; mv[1] = m0.y; mv[2] = m0.z; mv[3] = m0.w;
        mv[4] = m1.x; mv[5] = m1.y; mv[6] = m1.z; mv[7] = m1.w;
        unpack8(up0, p0); unpack8(up1, p1); unpack8(up2, p2);
#pragma unroll
        for (int u = 0; u < 8; ++u) {
            float e = __expf(mv[u] + m);
            s[u] += e;
            s2[u] += e * e;
            a0[u] += e * p0[u];
            a1[u] += e * p1[u];
            a2[u] += e * p2[u];
        }
    }

#pragma unroll
    for (int u = 0; u < 8; ++u) {
        part[kk][c0 + u] = s[u];
        part[kk][65 + c0 + u] = s2[u];
    }
    __syncthreads();
    if (t < 128) {
        int qq = t >> 6, c = t & 63;
        float sum = 0.f;
#pragma unroll
        for (int x = 0; x < 32; ++x) sum += part[x][qq * 65 + c];
        if (qq == 0) red_s[c] = sum; else red_s2[c] = sum;
    }
    __syncthreads();
#pragma unroll
    for (int u = 0; u < 8; ++u) {
        part[kk][c0 + u] = a0[u];
        part[kk][65 + c0 + u] = a1[u];
        part[kk][130 + c0 + u] = a2[u];
    }
    __syncthreads();
    if (t < 192) {
        int d = t >> 6, c = t & 63;
        float sum = 0.f;
#pragma unroll
        for (int x = 0; x < 32; ++x) sum += part[x][d * 65 + c];
        float sv = red_s[c];
        float scale = sqrtf(red_s2[c]) / (sv * sv);
        out_s[d][c] = sum * scale;
    }
    __syncthreads();
    if (t < 192) {
        int d = t >> 6, o = t & 63;
        float acc = b_eo[o];
        const float* wr = W_eo + o * 64;
#pragma unroll
        for (int c4 = 0; c4 < 64; c4 += 4) {
            float4 w = *(const float4*)(wr + c4);
            acc += out_s[d][c4 + 0] * w.x;
            acc += out_s[d][c4 + 1] * w.y;
            acc += out_s[d][c4 + 2] * w.z;
            acc += out_s[d][c4 + 3] * w.w;
        }
        out[(size_t)bq * 192 + t] = acc;
    }
}

// ---------------------------------------------------------------------------
// Inv attention, 2 q-rows per block (grid 1024). Shares proj loads across q.
// ---------------------------------------------------------------------------
__global__ __launch_bounds__(256) void k_inv_attn2(
    const float* __restrict__ inv_msg,  // [B,256,256,16] fp32
    const int* __restrict__ adj,        // [B,256,256]
    const u16* __restrict__ proj,       // [B,256,256] bf16 (ws)
    float* __restrict__ out_rows)       // [2048,256] fp32 (ws)
{
    int bq2 = blockIdx.x;               // [0,1024), 2 q's each
    int b = bq2 >> 7;
    int t = threadIdx.x;

    __shared__ float maskv[2][256];
    __shared__ int anyflag[2];
    __shared__ float p_s[2][256][16];
    __shared__ float spart[2][16][16], s2part[2][16][16];
    __shared__ float sh_s[2][16], sh_s2[2][16];
    __shared__ float red[4][2][256];

    if (t < 2) anyflag[t] = 0;
    __syncthreads();
    int a0 = adj[((size_t)bq2 * 2 + 0) * 256 + t];
    int a1 = adj[((size_t)bq2 * 2 + 1) * 256 + t];
    if (a0 != 0) anyflag[0] = 1;
    if (a1 != 0) anyflag[1] = 1;
    __syncthreads();
    maskv[0][t] = (a0 == 0 && anyflag[0] != 0) ? NINF : 0.0f;
    maskv[1][t] = (a1 == 0 && anyflag[1] != 0) ? NINF : 0.0f;
    __syncthreads();

    // pass 1: exps + per-head s, s2 partials
    {
        int h = t & 15, kk = t >> 4;
#pragma unroll
        for (int q = 0; q < 2; ++q) {
            const float* mb = inv_msg + ((size_t)bq2 * 2 + q) * 4096;
            float ss = 0.f, ss2 = 0.f;
#pragma unroll
            for (int j = 0; j < 16; ++j) {
                int k = kk + 16 * j;
                float e = __expf(mb[k * 16 + h] + maskv[q][k]);
                p_s[q][k][h] = e;
                ss += e; ss2 += e * e;
            }
            spart[q][kk][h] = ss;
            s2part[q][kk][h] = ss2;
        }
    }
    __syncthreads();
    if (t < 64) {
        int q = t >> 5, sel = (t >> 4) & 1, h = t & 15;
        float sum = 0.f;
        if (sel == 0) {
#pragma unroll
            for (int kk = 0; kk < 16; ++kk) sum += spart[q][kk][h];
            sh_s[q][h] = sum;
        } else {
#pragma unroll
            for (int kk = 0; kk < 16; ++kk) sum += s2part[q][kk][h];
            sh_s2[q][h] = sum;
        }
    }
    __syncthreads();

    // pass 2: out_i[q,h,e] = sum_k p[q,k,h] * proj[b,k,h*16+e]
    {
        int kk2 = t >> 6, h = (t >> 2) & 15, eg = t & 3;
        float acc0[4] = {0.f, 0.f, 0.f, 0.f};
        float acc1[4] = {0.f, 0.f, 0.f, 0.f};
        const u16* pb = proj + (size_t)b * 65536 + h * 16 + eg * 4;
        for (int j = 0; j < 64; ++j) {
            int k = kk2 + 4 * j;
            uint2 u = *(const uint2*)(pb + (size_t)k * 256);
            float w[4]; unpack4(u, w);
            float pq0 = p_s[0][k][h];
            float pq1 = p_s[1][k][h];
#pragma unroll
            for (int ii = 0; ii < 4; ++ii) {
                acc0[ii] += pq0 * w[ii];
                acc1[ii] += pq1 * w[ii];
            }
        }
#pragma unroll
        for (int ii = 0; ii < 4; ++ii) {
            red[kk2][0][h * 16 + eg * 4 + ii] = acc0[ii];
            red[kk2][1][h * 16 + eg * 4 + ii] = acc1[ii];
        }
    }
    __syncthreads();
    {
        int h = t >> 4;
#pragma unroll
        for (int q = 0; q < 2; ++q) {
            float sum = red[0][q][t] + red[1][q][t] + red[2][q][t] + red[3][q][t];
            float sv = sh_s[q][h];
            out_rows[((size_t)bq2 * 2 + q) * 256 + t] = sum * sqrtf(sh_s2[q][h]) / (sv * sv);
        }
    }
}

// ---------------------------------------------------------------------------
extern "C" void kernel_launch(void* const* d_in, const int* in_sizes, int n_in,
                              void* d_out, int out_size, void* d_ws, size_t ws_size,
                              hipStream_t stream) {
    (void)in_sizes; (void)n_in; (void)out_size; (void)ws_size;

    const float* v_equi   = (const float*)d_in[0];
    const float* v_inv    = (const float*)d_in[1];
    const float* equi_msg = (const float*)d_in[2];
    const float* inv_msg  = (const float*)d_in[3];
    const int*   adj      = (const int*)d_in[4];
    const float* W_coord  = (const float*)d_in[5];
    const float* W_eo     = (const float*)d_in[6];
    const float* b_eo     = (const float*)d_in[7];
    const float* W_in     = (const float*)d_in[8];
    const float* b_in     = (const float*)d_in[9];
    const float* W_out    = (const float*)d_in[10];
    const float* b_out    = (const float*)d_in[11];
    float* out = (float*)d_out;

    char* ws = (char*)d_ws;
    u16*   proj_equi = (u16*)(ws);                        // 786432 B
    u16*   proj_inv  = (u16*)(ws + 786432);               // 1048576 B
    float* out_rows  = (float*)(ws + 786432 + 1048576);   // 2097152 B

    k_prologue<<<dim3(640), dim3(256), 0, stream>>>(
        v_inv, W_in, b_in, proj_inv, v_equi, W_coord, proj_equi);
    k_equi_attn<<<dim3(2048), dim3(256), 0, stream>>>(
        equi_msg, adj, proj_equi, W_eo, b_eo, out);
    k_inv_attn2<<<dim3(1024), dim3(256), 0, stream>>>(
        inv_msg, adj, proj_inv, out_rows);
    k_rowgemm_tof32<<<dim3(256), dim3(256), 0, stream>>>(
        out_rows, W_out, b_out, out + 393216);
}